// Round 3
// baseline (375.309 us; speedup 1.0000x reference)
//
#include <hip/hip_runtime.h>

// Problem constants
#define B_    256
#define L_    2000
#define KL_   18
#define K2_   64
#define KN_   128
#define PAD_  4
#define LOUT_ 1990

// Tiling
#define TI_   256            // output positions per block-itile
#define NPOS_ 274            // TI_ + KL_ p-rows needed
#define PSTR_ 16             // bf16 per p-row (32B, tight) -> contiguous 1KB wave reads
#define BB_   8              // batch images per block (weight/prologue amortization)

typedef __attribute__((ext_vector_type(8)))  short bf16x8;
typedef __attribute__((ext_vector_type(16))) float f32x16;

__device__ __forceinline__ unsigned short f2bf(float f) {
    unsigned u = __float_as_uint(f);
    return (unsigned short)((u + 0x7fffu + ((u >> 16) & 1u)) >> 16);   // RTN-even
}
__device__ __forceinline__ float bf2f(unsigned short s) {
    return __uint_as_float(((unsigned)s) << 16);
}

__device__ __forceinline__ float4 load_x4(const float* __restrict__ x, int b, int dir, int q) {
    int m = q - PAD_;
    if (m < 0 || m >= L_) return make_float4(0.f, 0.f, 0.f, 0.f);
    int l = dir ? (L_ - 1 - m) : m;
    const float* p = x + ((size_t)b * L_ + l) * 4;   // [B,L,C] channel-last
    return *reinterpret_cast<const float4*>(p);
}

__global__ __launch_bounds__(256, 2)
void markonv_mfma2(const float* __restrict__ x,
                   const float* __restrict__ Wf,
                   const float* __restrict__ Wr,
                   const float* __restrict__ kwf,
                   const float* __restrict__ kwr,
                   float* __restrict__ out) {
    __shared__ __align__(16) unsigned short phi[NPOS_ * PSTR_];   // 8.8 KB
    __shared__ __align__(16) unsigned short plo[NPOS_ * PSTR_];   // 8.8 KB

    const int tid    = threadIdx.x;
    const int itile  = blockIdx.x;           // 0..7
    const int bgroup = blockIdx.y;           // 0..31
    const int dir    = blockIdx.z;           // 0..1
    const int i0     = itile * TI_;

    const float* W  = dir ? Wr  : Wf;
    const float* kw = dir ? kwr : kwf;

    const int wave = tid >> 6;
    const int lane = tid & 63;
    const int col  = lane & 31;              // MFMA col / A row
    const int h    = lane >> 5;              // contract-half select
    const int cd0  = h * 8;

    // ---- A-fragments for BOTH k-groups: masked weights (144 VGPR) ----
    bf16x8 af0[KL_], af1[KL_];
    #pragma unroll
    for (int kg = 0; kg < 2; ++kg) {
        int kglob = kg * 32 + col;
        float kw0 = kw[kglob];
        float kw1 = kw[K2_ + kglob];
        #pragma unroll
        for (int j = 0; j < KL_; ++j) {
            float fj = (float)j;
            float m = 1.f / (1.f + __expf(-(fj - kw0)))
                    + 1.f / (1.f + __expf(-(kw1 - fj))) - 1.f;
            bf16x8 a;
            #pragma unroll
            for (int e = 0; e < 8; ++e) {
                float wv = W[(size_t)(j * 16 + cd0 + e) * K2_ + kglob] * m;
                a[e] = (short)f2bf(wv);
            }
            if (kg == 0) af0[j] = a; else af1[j] = a;
        }
    }

    for (int bb = 0; bb < BB_; ++bb) {
        const int b = bgroup * BB_ + bb;
        __syncthreads();   // previous iter's readers done before overwrite

        // ---- pair products p[pos][cd], hi/lo split, tight 32B rows ----
        for (int li = tid; li < NPOS_; li += 256) {
            int q = i0 + li;
            float4 xa = load_x4(x, b, dir, q);
            float4 xb = load_x4(x, b, dir, q + 1);
            float va[4] = {xa.x, xa.y, xa.z, xa.w};
            float vb[4] = {xb.x, xb.y, xb.z, xb.w};
            unsigned* ph = (unsigned*)&phi[li * PSTR_];
            unsigned* pl = (unsigned*)&plo[li * PSTR_];
            #pragma unroll
            for (int c = 0; c < 4; ++c) {
                #pragma unroll
                for (int d = 0; d < 4; d += 2) {
                    float p0 = va[c] * vb[d];
                    float p1 = va[c] * vb[d + 1];
                    unsigned short h0 = f2bf(p0), h1 = f2bf(p1);
                    unsigned short l0 = f2bf(p0 - bf2f(h0)), l1 = f2bf(p1 - bf2f(h1));
                    ph[c * 2 + d / 2] = (unsigned)h0 | ((unsigned)h1 << 16);
                    pl[c * 2 + d / 2] = (unsigned)l0 | ((unsigned)l1 << 16);
                }
            }
        }
        __syncthreads();

        // ---- MFMA: wave owns subtiles {2w, 2w+1}; computes both k-groups ----
        #pragma unroll
        for (int ss = 0; ss < 2; ++ss) {
            const int s = wave * 2 + ss;
            f32x16 c0, c1;
            #pragma unroll
            for (int r = 0; r < 16; ++r) { c0[r] = 0.f; c1[r] = 0.f; }

            const int base = (s * 32 + col) * PSTR_ + cd0;   // ushort index
            #pragma unroll
            for (int j = 0; j < KL_; ++j) {
                bf16x8 bh = *(const bf16x8*)&phi[base + j * PSTR_];
                bf16x8 bl = *(const bf16x8*)&plo[base + j * PSTR_];
                c0 = __builtin_amdgcn_mfma_f32_32x32x16_bf16(af0[j], bh, c0, 0, 0, 0);
                c1 = __builtin_amdgcn_mfma_f32_32x32x16_bf16(af1[j], bh, c1, 0, 0, 0);
                c0 = __builtin_amdgcn_mfma_f32_32x32x16_bf16(af0[j], bl, c0, 0, 0, 0);
                c1 = __builtin_amdgcn_mfma_f32_32x32x16_bf16(af1[j], bl, c1, 0, 0, 0);
            }

            // stores: C/D layout col=lane&31, row=(r&3)+8*(r>>2)+4*h  [m74/m101]
            const int ig = i0 + s * 32 + col;
            if (ig < LOUT_) {
                float* ob = out + ((size_t)b * KN_ + (size_t)dir * K2_) * LOUT_ + ig;
                const int rbase = 4 * h;
                #pragma unroll
                for (int r = 0; r < 16; ++r) {
                    int row = (r & 3) + 8 * (r >> 2) + rbase;
                    ob[(size_t)row * LOUT_] = c0[r];
                    ob[(size_t)(row + 32) * LOUT_] = c1[r];
                }
            }
        }
    }
}

extern "C" void kernel_launch(void* const* d_in, const int* in_sizes, int n_in,
                              void* d_out, int out_size, void* d_ws, size_t ws_size,
                              hipStream_t stream) {
    const float* x   = (const float*)d_in[0];
    const float* Wf  = (const float*)d_in[1];
    const float* Wr  = (const float*)d_in[2];
    const float* kwf = (const float*)d_in[3];
    const float* kwr = (const float*)d_in[4];
    float* out = (float*)d_out;

    dim3 grid(8 /*itiles*/, B_ / BB_, 2 /*dir*/);
    markonv_mfma2<<<grid, 256, 0, stream>>>(x, Wf, Wr, kwf, kwr, out);
}